// Round 1
// baseline (3442.736 us; speedup 1.0000x reference)
//
#include <hip/hip_runtime.h>
#include <math.h>

#define Bn 2048
#define Cn 256
#define Tn 512
#define VTHf 3.0f

// ---------------------------------------------------------------------------
// Wr transpose: WrT[j][c] = Wr[c][j]  (so recurrent column read is coalesced)
// ---------------------------------------------------------------------------
__global__ void transpose_kernel(const float* __restrict__ Wr, float* __restrict__ WrT)
{
    WrT[(size_t)blockIdx.x * Cn + threadIdx.x] =
        Wr[(size_t)threadIdx.x * Cn + blockIdx.x];
}

// ---------------------------------------------------------------------------
// GEMM: Y[b, t - t0, c] = sum_k x[b, k, t] * Wf[c, k]   for t in [t0, t0+Tc)
// x: [B, C, T] fp32, Wf: [C, C] fp32, Y: [B, Tc, C] fp32
// Tiles: 64 t x 64 c, BK=16; 256 threads, 4x4 micro-tile per thread.
// ---------------------------------------------------------------------------
__global__ __launch_bounds__(256) void gemm_kernel(
    const float* __restrict__ x, const float* __restrict__ Wf,
    float* __restrict__ Y, int t0, int Tc)
{
    const int nTt  = Tc >> 6;
    const int tt   = blockIdx.x % nTt;
    const int cc   = blockIdx.x / nTt;   // 0..3
    const int b    = blockIdx.y;
    const int tbase = t0 + tt * 64;
    const int cbase = cc * 64;

    __shared__ float As[16][64];   // [k][t]
    __shared__ float Ws[16][68];   // [k][c], padded row (68*4=272B, 16B aligned)

    const int tid = threadIdx.x;
    const int tx  = tid & 15;      // c micro group
    const int ty  = tid >> 4;      // t micro group

    float acc[4][4];
    #pragma unroll
    for (int i = 0; i < 4; ++i)
        #pragma unroll
        for (int j = 0; j < 4; ++j) acc[i][j] = 0.f;

    const float* xb = x + (size_t)b * Cn * Tn;

    const int lt = tid & 63;       // t within tile (coalesced along T)
    const int lk = tid >> 6;       // 0..3
    const int wk = tid & 15;       // k within tile (coalesced along K of Wf)
    const int wc = tid >> 4;       // 0..15

    for (int k0 = 0; k0 < Cn; k0 += 16) {
        #pragma unroll
        for (int p = 0; p < 4; ++p)
            As[lk + 4 * p][lt] = xb[(size_t)(k0 + lk + 4 * p) * Tn + tbase + lt];
        #pragma unroll
        for (int p = 0; p < 4; ++p)
            Ws[wk][wc + 16 * p] = Wf[(size_t)(cbase + wc + 16 * p) * Cn + k0 + wk];
        __syncthreads();

        #pragma unroll
        for (int kk = 0; kk < 16; ++kk) {
            const float4 a4 = *(const float4*)&As[kk][ty * 4];
            const float4 w4 = *(const float4*)&Ws[kk][tx * 4];
            const float a[4] = {a4.x, a4.y, a4.z, a4.w};
            const float w[4] = {w4.x, w4.y, w4.z, w4.w};
            #pragma unroll
            for (int i = 0; i < 4; ++i)
                #pragma unroll
                for (int j = 0; j < 4; ++j)
                    acc[i][j] = fmaf(a[i], w[j], acc[i][j]);
        }
        __syncthreads();
    }

    float* Yb = Y + ((size_t)b * Tc + (size_t)(tbase - t0)) * Cn + cbase;
    #pragma unroll
    for (int i = 0; i < 4; ++i) {
        float4 o = make_float4(acc[i][0], acc[i][1], acc[i][2], acc[i][3]);
        *(float4*)&Yb[(size_t)(ty * 4 + i) * Cn + tx * 4] = o;
    }
}

// ---------------------------------------------------------------------------
// Sequential LIF/WTA scan, one wave per batch row, 4 channels per lane.
// v' = v*decay + Y[t] + (fired ? WrT[j_prev] : 0)
// j = first argmax_c v'; fired = v'_max >= VTH; hard reset v'>=VTH -> 0.
// Output (final chunk): out = exp(pre_v) where pre_v = v' of last step.
// ---------------------------------------------------------------------------
__global__ __launch_bounds__(256) void scan_kernel(
    const float* __restrict__ Y, const float* __restrict__ WrT,
    float* __restrict__ vstate, int* __restrict__ jstate,
    float* __restrict__ out, int t0, int t1, int Tc)
{
    const int wave = threadIdx.x >> 6;
    const int lane = threadIdx.x & 63;
    const int b    = blockIdx.x * 4 + wave;
    const int c0   = lane * 4;

    const float DECAY = (float)(1.0 - 1.0 / 6.0);   // fp32(0.8333333333333334) = 0x3F555556

    float4 v;
    int jf;
    if (t0 == 0) {
        v = make_float4(0.f, 0.f, 0.f, 0.f);
        jf = -1;
    } else {
        v  = *(const float4*)&vstate[(size_t)b * Cn + c0];
        jf = jstate[b];
    }

    const float4* Yb = (const float4*)(Y + (size_t)b * Tc * Cn) + lane; // stride Cn/4=64 float4s per step
    float4 ycur = Yb[0];
    float4 pv = v;

    for (int t = t0; t < t1; ++t) {
        float4 ynext;
        if (t + 1 < t1) ynext = Yb[(size_t)(t + 1 - t0) * 64];

        float4 inp = ycur;
        if (jf >= 0) {
            const float4 r = *(const float4*)&WrT[(size_t)jf * Cn + c0];
            inp.x += r.x; inp.y += r.y; inp.z += r.z; inp.w += r.w;
        }
        // match reference rounding: (v * decay) then (+ inp), no contraction
        v.x = __fadd_rn(__fmul_rn(v.x, DECAY), inp.x);
        v.y = __fadd_rn(__fmul_rn(v.y, DECAY), inp.y);
        v.z = __fadd_rn(__fmul_rn(v.z, DECAY), inp.z);
        v.w = __fadd_rn(__fmul_rn(v.w, DECAY), inp.w);

        // local first-argmax over the 4 owned channels (strict > keeps lowest idx)
        float mv = v.x; int mi = c0;
        if (v.y > mv) { mv = v.y; mi = c0 + 1; }
        if (v.z > mv) { mv = v.z; mi = c0 + 2; }
        if (v.w > mv) { mv = v.w; mi = c0 + 3; }

        // wave-wide butterfly: max with first-index tie-break (assoc+comm)
        #pragma unroll
        for (int off = 32; off; off >>= 1) {
            float ov = __shfl_xor(mv, off);
            int   oi = __shfl_xor(mi, off);
            if (ov > mv || (ov == mv && oi < mi)) { mv = ov; mi = oi; }
        }
        jf = (mv >= VTHf) ? mi : -1;

        pv = v;  // pre-reset membrane potential
        if (v.x >= VTHf) v.x = 0.f;
        if (v.y >= VTHf) v.y = 0.f;
        if (v.z >= VTHf) v.z = 0.f;
        if (v.w >= VTHf) v.w = 0.f;

        ycur = ynext;
    }

    if (t1 == Tn) {
        float4 o = make_float4(expf(pv.x), expf(pv.y), expf(pv.z), expf(pv.w));
        *(float4*)&out[(size_t)b * Cn + c0] = o;
    } else {
        *(float4*)&vstate[(size_t)b * Cn + c0] = v;
        if (lane == 0) jstate[b] = jf;
    }
}

// ---------------------------------------------------------------------------
extern "C" void kernel_launch(void* const* d_in, const int* in_sizes, int n_in,
                              void* d_out, int out_size, void* d_ws, size_t ws_size,
                              hipStream_t stream)
{
    const float* x  = (const float*)d_in[0];
    const float* Wf = (const float*)d_in[1];
    const float* Wr = (const float*)d_in[2];
    float* out = (float*)d_out;

    char* ws = (char*)d_ws;
    float* WrT = (float*)(ws);
    float* vst = (float*)(ws + (size_t)Cn * Cn * 4);
    int*   jst = (int*)  (ws + (size_t)Cn * Cn * 4 + (size_t)Bn * Cn * 4);
    size_t ybase = (size_t)Cn * Cn * 4 + (size_t)Bn * Cn * 4 + (size_t)Bn * 4;
    ybase = (ybase + 255) & ~(size_t)255;
    float* Y = (float*)(ws + ybase);
    size_t avail = ws_size > ybase ? ws_size - ybase : 0;

    // chunk T so Y fits in workspace (Tc must be a multiple of 64)
    int Tc = 64;
    if      ((size_t)Bn * Cn * 512 * 4 <= avail) Tc = 512;
    else if ((size_t)Bn * Cn * 256 * 4 <= avail) Tc = 256;
    else if ((size_t)Bn * Cn * 128 * 4 <= avail) Tc = 128;

    transpose_kernel<<<dim3(Cn), dim3(Cn), 0, stream>>>(Wr, WrT);

    for (int t0 = 0; t0 < Tn; t0 += Tc) {
        dim3 g((unsigned)((Tc >> 6) * 4), (unsigned)Bn);
        gemm_kernel<<<g, 256, 0, stream>>>(x, Wf, Y, t0, Tc);
        scan_kernel<<<dim3(Bn / 4), 256, 0, stream>>>(Y, WrT, vst, jst, out,
                                                      t0, t0 + Tc, Tc);
    }
}